// Round 1
// baseline (1198.601 us; speedup 1.0000x reference)
//
#include <hip/hip_runtime.h>
#include <math.h>

#define B_  32
#define S_  4096
#define E_  256
#define A_  256
#define DE_ 512

#define TS  64    // s-rows per block in scores kernel
#define KC  32    // k chunk
#define SCH 128   // s-chunk per block in attend kernel

// ---- Kernel A: proj[b][a] = bias[a] + sum_d dh[b][d] * W[a][d]
__global__ __launch_bounds__(256) void proj_kernel(
    const float* __restrict__ dh, const float* __restrict__ W,
    const float* __restrict__ bias, float* __restrict__ proj)
{
    __shared__ float dh_lds[E_];
    const int b = blockIdx.x;
    const int a = threadIdx.x;
    dh_lds[a] = dh[b * E_ + a];
    __syncthreads();
    float acc = bias[a];
    const float* wrow = W + (size_t)a * DE_;
    #pragma unroll
    for (int d = 0; d < E_; d += 4) {
        float4 w = *(const float4*)(wrow + d);
        acc += dh_lds[d] * w.x + dh_lds[d+1] * w.y
             + dh_lds[d+2] * w.z + dh_lds[d+3] * w.w;
    }
    proj[b * A_ + a] = acc;
}

// ---- Kernel B: scores[b][s] = sum_a tanh(proj[b][a] + eo[b,s,:].We[a,:])
//                nsq[b][s]    = ||eo[b,s,:]||^2
// eo layout is (S,B,E): eo[s*B_*E_ + b*E_ + e]
__global__ __launch_bounds__(256) void scores_kernel(
    const float* __restrict__ eo, const float* __restrict__ W,
    const float* __restrict__ proj, float* __restrict__ scores,
    float* __restrict__ nsq)
{
    __shared__ __align__(16) float eo_lds[TS][36];    // k-chunk of 64 s-rows (pad 36)
    __shared__ __align__(16) float We_lds[KC][260];   // transposed We chunk (pad 260)

    const int tid = threadIdx.x;
    const int b   = blockIdx.x & (B_ - 1);
    const int sc  = blockIdx.x / B_;
    const int s0  = sc * TS;
    const int ta  = tid & 31;   // a-group: 32 threads cover A=256 with 8 each
    const int sg  = tid >> 5;   // s-group: 8 groups of 8 rows
    const int a0  = ta * 8;
    const int r0  = sg * 8;

    float acc[8][8];
    #pragma unroll
    for (int i = 0; i < 8; ++i)
        #pragma unroll
        for (int j = 0; j < 8; ++j) acc[i][j] = 0.f;
    float nacc[8];
    #pragma unroll
    for (int i = 0; i < 8; ++i) nacc[i] = 0.f;

    for (int kc = 0; kc < E_; kc += KC) {
        // stage eo chunk: 64 rows x 32 floats = 512 float4, 2 per thread
        #pragma unroll
        for (int it = 0; it < 2; ++it) {
            int lin = it * 256 + tid;
            int row = lin >> 3, kq = lin & 7;
            float4 v = *(const float4*)(eo + (size_t)(s0 + row) * (B_ * E_)
                                           + b * E_ + kc + kq * 4);
            *(float4*)&eo_lds[row][kq * 4] = v;
        }
        // stage We chunk transposed: 256 a x 32 k = 2048 float4, 8 per thread
        #pragma unroll
        for (int it = 0; it < 8; ++it) {
            int lin = it * 256 + tid;
            int a = lin >> 3, kq = lin & 7;
            float4 v = *(const float4*)(W + (size_t)a * DE_ + E_ + kc + kq * 4);
            We_lds[kq * 4 + 0][a] = v.x;
            We_lds[kq * 4 + 1][a] = v.y;
            We_lds[kq * 4 + 2][a] = v.z;
            We_lds[kq * 4 + 3][a] = v.w;
        }
        __syncthreads();

        #pragma unroll
        for (int k = 0; k < KC; k += 4) {
            float4 e4[8];
            #pragma unroll
            for (int i = 0; i < 8; ++i)
                e4[i] = *(const float4*)&eo_lds[r0 + i][k];
            if (ta == 0) {  // one lane per s-group accumulates squared norms
                #pragma unroll
                for (int i = 0; i < 8; ++i)
                    nacc[i] += e4[i].x*e4[i].x + e4[i].y*e4[i].y
                             + e4[i].z*e4[i].z + e4[i].w*e4[i].w;
            }
            #pragma unroll
            for (int kk = 0; kk < 4; ++kk) {
                float4 wA = *(const float4*)&We_lds[k + kk][a0];
                float4 wB = *(const float4*)&We_lds[k + kk][a0 + 4];
                float wv[8] = {wA.x, wA.y, wA.z, wA.w, wB.x, wB.y, wB.z, wB.w};
                #pragma unroll
                for (int i = 0; i < 8; ++i) {
                    float e = (kk == 0) ? e4[i].x : (kk == 1) ? e4[i].y
                            : (kk == 2) ? e4[i].z : e4[i].w;
                    #pragma unroll
                    for (int j = 0; j < 8; ++j)
                        acc[i][j] = fmaf(e, wv[j], acc[i][j]);
                }
            }
        }
        __syncthreads();
    }

    // epilogue: tanh + sum over a
    float pr[8];
    #pragma unroll
    for (int j = 0; j < 8; ++j) pr[j] = proj[b * A_ + a0 + j];

    float* red = &We_lds[0][0];  // reuse as [64][33] scratch (safe: past last sync)
    #pragma unroll
    for (int i = 0; i < 8; ++i) {
        float ssum = 0.f;
        #pragma unroll
        for (int j = 0; j < 8; ++j) ssum += tanhf(pr[j] + acc[i][j]);
        red[(r0 + i) * 33 + ta] = ssum;
    }
    if (ta == 0) {
        #pragma unroll
        for (int i = 0; i < 8; ++i) nsq[b * S_ + s0 + r0 + i] = nacc[i];
    }
    __syncthreads();
    if (tid < TS) {
        float ssum = 0.f;
        #pragma unroll
        for (int t = 0; t < 32; ++t) ssum += red[tid * 33 + t];
        scores[b * S_ + s0 + tid] = ssum;
    }
}

// ---- Kernel C: softmax over S per b; attn_map = p * sqrt(nsq); zero attended
// scores lives in out[B_*E_ ...] and is overwritten in-place with attn_map
// (each thread reads exactly the indices it later writes).
__global__ __launch_bounds__(256) void softmax_kernel(
    const float* __restrict__ nsq, float* __restrict__ p, float* __restrict__ out)
{
    __shared__ float red[256];
    const int b = blockIdx.x;
    const int tid = threadIdx.x;
    float* scores = out + B_ * E_;

    float v[16];
    float m = -1e30f;
    #pragma unroll
    for (int i = 0; i < 16; ++i) {
        v[i] = scores[b * S_ + i * 256 + tid];
        m = fmaxf(m, v[i]);
    }
    red[tid] = m;
    __syncthreads();
    for (int off = 128; off > 0; off >>= 1) {
        if (tid < off) red[tid] = fmaxf(red[tid], red[tid + off]);
        __syncthreads();
    }
    m = red[0];
    __syncthreads();
    float sum = 0.f;
    #pragma unroll
    for (int i = 0; i < 16; ++i) { v[i] = expf(v[i] - m); sum += v[i]; }
    red[tid] = sum;
    __syncthreads();
    for (int off = 128; off > 0; off >>= 1) {
        if (tid < off) red[tid] += red[tid + off];
        __syncthreads();
    }
    const float inv = 1.f / red[0];
    #pragma unroll
    for (int i = 0; i < 16; ++i) {
        int s = i * 256 + tid;
        float pp = v[i] * inv;
        p[b * S_ + s] = pp;
        scores[b * S_ + s] = pp * sqrtf(nsq[b * S_ + s]);  // attn_map in place
    }
    out[b * E_ + tid] = 0.f;  // zero attended region for kernel D's atomics
}

// ---- Kernel D: attended[b][e] += sum_{s in chunk} p[b][s] * eo[s][b][e]
__global__ __launch_bounds__(256) void attend_kernel(
    const float* __restrict__ eo, const float* __restrict__ p,
    float* __restrict__ out)
{
    const int b  = blockIdx.x & (B_ - 1);
    const int ch = blockIdx.x / B_;
    const int e  = threadIdx.x;
    const int s0 = ch * SCH;
    float acc = 0.f;
    #pragma unroll 4
    for (int s = 0; s < SCH; ++s) {
        acc = fmaf(p[b * S_ + s0 + s],
                   eo[(size_t)(s0 + s) * (B_ * E_) + b * E_ + e], acc);
    }
    atomicAdd(&out[b * E_ + e], acc);
}

extern "C" void kernel_launch(void* const* d_in, const int* in_sizes, int n_in,
                              void* d_out, int out_size, void* d_ws, size_t ws_size,
                              hipStream_t stream)
{
    const float* dh   = (const float*)d_in[0];  // (1,B,D)
    const float* eo   = (const float*)d_in[1];  // (S,B,E)
    const float* W    = (const float*)d_in[2];  // (A, D+E)
    const float* bias = (const float*)d_in[3];  // (A,)
    float* out = (float*)d_out;                 // [attended 8192 | attn_map 131072]
    float* ws  = (float*)d_ws;

    float* proj = ws;                  // 8192 floats
    float* nsq  = ws + 8192;           // 131072 floats
    float* p    = ws + 8192 + S_ * B_; // 131072 floats
    float* scores = out + B_ * E_;     // staged in attn_map slot, overwritten by softmax

    proj_kernel   <<<B_,              256, 0, stream>>>(dh, W, bias, proj);
    scores_kernel <<<B_ * (S_ / TS),  256, 0, stream>>>(eo, W, proj, scores, nsq);
    softmax_kernel<<<B_,              256, 0, stream>>>(nsq, p, out);
    attend_kernel <<<B_ * (S_ / SCH), 256, 0, stream>>>(eo, p, out);
}

// Round 2
// 353.161 us; speedup vs baseline: 3.3939x; 3.3939x over previous
//
#include <hip/hip_runtime.h>
#include <math.h>

#define B_  32
#define S_  4096
#define E_  256
#define A_  256
#define DE_ 512
#define SCH 128   // s-chunk per block in attend kernel

typedef __attribute__((ext_vector_type(8))) short short8;
typedef __attribute__((ext_vector_type(4))) float f32x4;

__device__ inline unsigned short f2bf(float x) {
    unsigned int u = __float_as_uint(x);
    u += 0x7FFFu + ((u >> 16) & 1u);      // round-to-nearest-even
    return (unsigned short)(u >> 16);
}
__device__ inline float bf2f(unsigned short h) {
    return __uint_as_float(((unsigned int)h) << 16);
}
__device__ inline float tanh_fast(float x) {
    x = fminf(fmaxf(x, -15.f), 15.f);     // avoid inf/inf
    float t = __expf(2.f * x);
    return (t - 1.f) / (t + 1.f);
}

// ---- Kernel W-prep: split We = W[:,256:] into bf16 hi/lo planes [A][E]
__global__ __launch_bounds__(256) void wprep_kernel(
    const float* __restrict__ W, unsigned short* __restrict__ weh,
    unsigned short* __restrict__ wel)
{
    int idx = blockIdx.x * 256 + threadIdx.x;   // 65536 total
    int a = idx >> 8, e = idx & 255;
    float x = W[a * DE_ + E_ + e];
    unsigned short h = f2bf(x);
    weh[idx] = h;
    wel[idx] = f2bf(x - bf2f(h));
}

// ---- Kernel A: proj[b][a] = bias[a] + sum_d dh[b][d] * W[a][d]
__global__ __launch_bounds__(256) void proj_kernel(
    const float* __restrict__ dh, const float* __restrict__ W,
    const float* __restrict__ bias, float* __restrict__ proj)
{
    __shared__ float dh_lds[E_];
    const int b = blockIdx.x;
    const int a = threadIdx.x;
    dh_lds[a] = dh[b * E_ + a];
    __syncthreads();
    float acc = bias[a];
    const float* wrow = W + (size_t)a * DE_;
    #pragma unroll
    for (int d = 0; d < E_; d += 4) {
        float4 w = *(const float4*)(wrow + d);
        acc += dh_lds[d] * w.x + dh_lds[d+1] * w.y
             + dh_lds[d+2] * w.z + dh_lds[d+3] * w.w;
    }
    proj[b * A_ + a] = acc;
}

// ---- Kernel B: scores[b][s] = sum_a tanh(proj[b][a] + eo[b,s,:].We[a,:])
//                nsq[b][s]    = ||eo[b,s,:]||^2
// Split-bf16 MFMA (3 products): block = 64 s x 256 a, wave = 64 s x 64 a.
// LDS fragment-linear layout: [kgroup(4)][row][8 bf16] -> 16B units.
__global__ __launch_bounds__(256, 3) void scores_kernel(
    const float* __restrict__ eo,
    const unsigned short* __restrict__ weh_g,
    const unsigned short* __restrict__ wel_g,
    const float* __restrict__ proj,
    float* __restrict__ scores, float* __restrict__ nsq)
{
    __shared__ __align__(16) unsigned short we_hl[2 * 4 * 256 * 8]; // hi units [0,1024), lo [1024,2048)
    __shared__ __align__(16) unsigned short eo_hl[2 * 4 * 64 * 8];  // hi units [0,256),  lo [256,512)
    __shared__ float proj_lds[A_];

    const int tid = threadIdx.x;
    const int b   = blockIdx.x & (B_ - 1);
    const int s0  = (blockIdx.x / B_) * 64;
    const int w   = tid >> 6;     // wave id 0..3 -> a-range w*64
    const int l   = tid & 63;
    const int lq  = l >> 4;       // quad 0..3 -> k-group
    const int lr  = l & 15;       // row/col within tile

    proj_lds[tid] = proj[b * A_ + tid];

    f32x4 acc[4][4];
    #pragma unroll
    for (int i = 0; i < 4; ++i) {
        #pragma unroll
        for (int j = 0; j < 4; ++j)
            acc[i][j] = (f32x4){0.f, 0.f, 0.f, 0.f};
    }

    // eo staging map: thread -> (row = tid&63, kgroup = tid>>6), 8 floats
    const int erow = tid & 63;
    const int ekg  = tid >> 6;
    const float* ebase = eo + (size_t)(s0 + erow) * (B_ * E_) + b * E_ + ekg * 8;
    const int arow = w * 64 + l;  // this wave's private We rows
    float nacc = 0.f;

    for (int kc = 0; kc < E_; kc += 32) {
        __syncthreads();
        // ---- stage eo chunk: load fp32, split to bf16 hi/lo, 2x ds_write_b128
        float4 v0 = *(const float4*)(ebase + kc);
        float4 v1 = *(const float4*)(ebase + kc + 4);
        float xs[8] = {v0.x, v0.y, v0.z, v0.w, v1.x, v1.y, v1.z, v1.w};
        unsigned int hp[4], lp[4];
        #pragma unroll
        for (int j = 0; j < 4; ++j) {
            float x0 = xs[2*j], x1 = xs[2*j+1];
            unsigned short h0 = f2bf(x0), h1 = f2bf(x1);
            unsigned short l0 = f2bf(x0 - bf2f(h0));
            unsigned short l1 = f2bf(x1 - bf2f(h1));
            hp[j] = (unsigned int)h0 | ((unsigned int)h1 << 16);
            lp[j] = (unsigned int)l0 | ((unsigned int)l1 << 16);
            nacc += x0 * x0 + x1 * x1;
        }
        *(uint4*)&eo_hl[(size_t)tid * 8]         = make_uint4(hp[0], hp[1], hp[2], hp[3]);
        *(uint4*)&eo_hl[(size_t)(256 + tid) * 8] = make_uint4(lp[0], lp[1], lp[2], lp[3]);
        // ---- stage We chunk via async global->LDS (bf16, pre-split, no conversion)
        #pragma unroll
        for (int kg = 0; kg < 4; ++kg) {
            const unsigned short* gh = weh_g + ((size_t)arow * E_ + kc + kg * 8);
            const unsigned short* gl = wel_g + ((size_t)arow * E_ + kc + kg * 8);
            __builtin_amdgcn_global_load_lds(
                (const __attribute__((address_space(1))) void*)gh,
                (__attribute__((address_space(3))) void*)&we_hl[(size_t)(kg * 256 + arow) * 8],
                16, 0, 0);
            __builtin_amdgcn_global_load_lds(
                (const __attribute__((address_space(1))) void*)gl,
                (__attribute__((address_space(3))) void*)&we_hl[(size_t)(1024 + kg * 256 + arow) * 8],
                16, 0, 0);
        }
        __syncthreads();
        // ---- compute: B-frags once, then A-frags per m-tile
        short8 bh[4], bl[4];
        #pragma unroll
        for (int nt = 0; nt < 4; ++nt) {
            int bunit = lq * 256 + w * 64 + nt * 16 + lr;
            bh[nt] = *(const short8*)&we_hl[(size_t)bunit * 8];
            bl[nt] = *(const short8*)&we_hl[(size_t)(1024 + bunit) * 8];
        }
        #pragma unroll
        for (int mt = 0; mt < 4; ++mt) {
            int aunit = lq * 64 + mt * 16 + lr;
            short8 ah = *(const short8*)&eo_hl[(size_t)aunit * 8];
            short8 al = *(const short8*)&eo_hl[(size_t)(256 + aunit) * 8];
            #pragma unroll
            for (int nt = 0; nt < 4; ++nt) {
                acc[mt][nt] = __builtin_amdgcn_mfma_f32_16x16x32_bf16(ah, bh[nt], acc[mt][nt], 0, 0, 0);
                acc[mt][nt] = __builtin_amdgcn_mfma_f32_16x16x32_bf16(ah, bl[nt], acc[mt][nt], 0, 0, 0);
                acc[mt][nt] = __builtin_amdgcn_mfma_f32_16x16x32_bf16(al, bh[nt], acc[mt][nt], 0, 0, 0);
            }
        }
    }
    __syncthreads();   // all fragment reads done before LDS reuse

    // ---- epilogue: tanh + reduce over a
    float* red4  = (float*)we_hl;        // [64 cols][65] floats
    float* npart = red4 + 64 * 65;       // [256] floats
    float pr[4];
    #pragma unroll
    for (int nt = 0; nt < 4; ++nt) pr[nt] = proj_lds[w * 64 + nt * 16 + lr];
    #pragma unroll
    for (int mt = 0; mt < 4; ++mt) {
        #pragma unroll
        for (int r = 0; r < 4; ++r) {
            float s = 0.f;
            #pragma unroll
            for (int nt = 0; nt < 4; ++nt)
                s += tanh_fast(pr[nt] + acc[mt][nt][r]);
            // C/D layout: col = lr (a-dim), row = mt*16 + lq*4 + r (s-dim)
            red4[(w * 16 + lr) * 65 + (mt * 16 + lq * 4 + r)] = s;
        }
    }
    npart[tid] = nacc;
    __syncthreads();
    if (tid < 64) {
        float s = 0.f;
        #pragma unroll 8
        for (int c = 0; c < 64; ++c) s += red4[c * 65 + tid];
        scores[b * S_ + s0 + tid] = s;
        nsq[b * S_ + s0 + tid] = npart[tid] + npart[tid + 64]
                               + npart[tid + 128] + npart[tid + 192];
    }
}

// ---- Kernel C: softmax over S per b; writes p (into nsq_p, aliased) and
// attn_map = p * sqrt(nsq) in place of scores; zeroes attended region.
__global__ __launch_bounds__(256) void softmax_kernel(
    float* __restrict__ nsq_p, float* __restrict__ out)
{
    __shared__ float red[256];
    const int b = blockIdx.x;
    const int tid = threadIdx.x;
    float* scores = out + B_ * E_;

    float v[16];
    float m = -1e30f;
    #pragma unroll
    for (int i = 0; i < 16; ++i) {
        v[i] = scores[b * S_ + i * 256 + tid];
        m = fmaxf(m, v[i]);
    }
    red[tid] = m;
    __syncthreads();
    for (int off = 128; off > 0; off >>= 1) {
        if (tid < off) red[tid] = fmaxf(red[tid], red[tid + off]);
        __syncthreads();
    }
    m = red[0];
    __syncthreads();
    float sum = 0.f;
    #pragma unroll
    for (int i = 0; i < 16; ++i) { v[i] = expf(v[i] - m); sum += v[i]; }
    red[tid] = sum;
    __syncthreads();
    for (int off = 128; off > 0; off >>= 1) {
        if (tid < off) red[tid] += red[tid + off];
        __syncthreads();
    }
    const float inv = 1.f / red[0];
    #pragma unroll
    for (int i = 0; i < 16; ++i) {
        int s = i * 256 + tid;
        float pp = v[i] * inv;
        float nq = nsq_p[b * S_ + s];
        nsq_p[b * S_ + s] = pp;                    // p overwrites nsq in place
        scores[b * S_ + s] = pp * sqrtf(nq);       // attn_map in place
    }
    out[b * E_ + tid] = 0.f;  // zero attended region for kernel D's atomics
}

// ---- Kernel D: attended[b][e] += sum_{s in chunk} p[b][s] * eo[s][b][e]
__global__ __launch_bounds__(256) void attend_kernel(
    const float* __restrict__ eo, const float* __restrict__ p,
    float* __restrict__ out)
{
    const int b  = blockIdx.x & (B_ - 1);
    const int ch = blockIdx.x / B_;
    const int e  = threadIdx.x;
    const int s0 = ch * SCH;
    float acc = 0.f;
    #pragma unroll 4
    for (int s = 0; s < SCH; ++s) {
        acc = fmaf(p[b * S_ + s0 + s],
                   eo[(size_t)(s0 + s) * (B_ * E_) + b * E_ + e], acc);
    }
    atomicAdd(&out[b * E_ + e], acc);
}

extern "C" void kernel_launch(void* const* d_in, const int* in_sizes, int n_in,
                              void* d_out, int out_size, void* d_ws, size_t ws_size,
                              hipStream_t stream)
{
    const float* dh   = (const float*)d_in[0];  // (1,B,D)
    const float* eo   = (const float*)d_in[1];  // (S,B,E)
    const float* W    = (const float*)d_in[2];  // (A, D+E)
    const float* bias = (const float*)d_in[3];  // (A,)
    float* out = (float*)d_out;                 // [attended 8192 | attn_map 131072]
    float* ws  = (float*)d_ws;

    float* projb = ws;                            // 8192 floats
    float* nsqp  = ws + 8192;                     // 131072 floats (nsq, then p)
    unsigned short* weh = (unsigned short*)(ws + 8192 + S_ * B_);  // 65536 bf16
    unsigned short* wel = weh + A_ * E_;                           // 65536 bf16
    float* scores = out + B_ * E_;  // staged in attn_map slot, overwritten by softmax

    wprep_kernel  <<<A_ * E_ / 256,   256, 0, stream>>>(W, weh, wel);
    proj_kernel   <<<B_,              256, 0, stream>>>(dh, W, bias, projb);
    scores_kernel <<<B_ * (S_ / 64),  256, 0, stream>>>(eo, weh, wel, projb, scores, nsqp);
    softmax_kernel<<<B_,              256, 0, stream>>>(nsqp, out);
    attend_kernel <<<B_ * (S_ / SCH), 256, 0, stream>>>(eo, nsqp, out);
}

// Round 3
// 271.952 us; speedup vs baseline: 4.4074x; 1.2986x over previous
//
#include <hip/hip_runtime.h>
#include <math.h>

#define B_  32
#define S_  4096
#define E_  256
#define A_  256
#define DE_ 512
#define SCH 128   // s-rows per block in attend kernel

typedef __attribute__((ext_vector_type(8))) short short8;
typedef __attribute__((ext_vector_type(4))) float f32x4;

__device__ inline unsigned short f2bf(float x) {
    unsigned int u = __float_as_uint(x);
    u += 0x7FFFu + ((u >> 16) & 1u);      // round-to-nearest-even
    return (unsigned short)(u >> 16);
}
__device__ inline float bf2f(unsigned short h) {
    return __uint_as_float(((unsigned int)h) << 16);
}
__device__ inline float tanh_fast(float x) {
    x = fminf(fmaxf(x, -15.f), 15.f);     // avoid inf/inf
    float t = __expf(2.f * x);
    return (t - 1.f) / (t + 1.f);
}

// ---- Kernel W-prep: pack We = W[:,256:] split to bf16 hi/lo in the scores
// kernel's LDS fragment-linear layout: unit index = c*2048 + plane*1024 +
// kg*256 + a, each unit = 8 bf16 (16 B) = We[a][c*32 + kg*8 .. +8].
// This makes the global->LDS staging loads lane-contiguous.
__global__ __launch_bounds__(256) void wprep_kernel(
    const float* __restrict__ W, unsigned short* __restrict__ wepk)
{
    const int idx = blockIdx.x * 256 + threadIdx.x;   // unit 0..16383
    const int c     = idx >> 11;
    const int r     = idx & 2047;
    const int plane = r >> 10;        // 0 = hi, 1 = lo
    const int kg    = (r >> 8) & 3;
    const int a     = r & 255;
    const float* src = W + (size_t)a * DE_ + E_ + c * 32 + kg * 8;
    unsigned int pk[4];
    #pragma unroll
    for (int j = 0; j < 4; ++j) {
        float x0 = src[2 * j], x1 = src[2 * j + 1];
        unsigned short h0 = f2bf(x0), h1 = f2bf(x1);
        unsigned short v0 = plane ? f2bf(x0 - bf2f(h0)) : h0;
        unsigned short v1 = plane ? f2bf(x1 - bf2f(h1)) : h1;
        pk[j] = (unsigned int)v0 | ((unsigned int)v1 << 16);
    }
    *(uint4*)&wepk[(size_t)idx * 8] = make_uint4(pk[0], pk[1], pk[2], pk[3]);
}

// ---- Kernel A: proj[b][a] = bias[a] + sum_d dh[b][d] * W[a][d]
__global__ __launch_bounds__(256) void proj_kernel(
    const float* __restrict__ dh, const float* __restrict__ W,
    const float* __restrict__ bias, float* __restrict__ proj)
{
    __shared__ float dh_lds[E_];
    const int b = blockIdx.x;
    const int a = threadIdx.x;
    dh_lds[a] = dh[b * E_ + a];
    __syncthreads();
    float acc = bias[a];
    const float* wrow = W + (size_t)a * DE_;
    #pragma unroll
    for (int d = 0; d < E_; d += 4) {
        float4 w = *(const float4*)(wrow + d);
        acc += dh_lds[d] * w.x + dh_lds[d+1] * w.y
             + dh_lds[d+2] * w.z + dh_lds[d+3] * w.w;
    }
    proj[b * A_ + a] = acc;
}

// ---- Kernel B: scores[b][s] = sum_a tanh(proj[b][a] + eo[b,s,:].We[a,:])
//                nsq[b][s]    = ||eo[b,s,:]||^2
// Split-bf16 MFMA (3 products): block = 64 s x 256 a, wave = 64 s x 64 a.
__global__ __launch_bounds__(256, 3) void scores_kernel(
    const float* __restrict__ eo,
    const unsigned short* __restrict__ wepk,
    const float* __restrict__ proj,
    float* __restrict__ scores, float* __restrict__ nsq)
{
    __shared__ __align__(16) unsigned short we_hl[2 * 4 * 256 * 8]; // hi units [0,1024), lo [1024,2048)
    __shared__ __align__(16) unsigned short eo_hl[2 * 4 * 64 * 8];  // hi units [0,256),  lo [256,512)
    __shared__ float proj_lds[A_];
    __shared__ float npart[512];

    const int tid = threadIdx.x;
    const int b   = blockIdx.x & (B_ - 1);
    const int s0  = (blockIdx.x / B_) * 64;
    const int w   = tid >> 6;     // wave id 0..3 -> a-range w*64
    const int l   = tid & 63;
    const int lq  = l >> 4;       // quad 0..3 -> k-group
    const int lr  = l & 15;       // row/col within tile

    proj_lds[tid] = proj[b * A_ + tid];

    f32x4 acc[4][4];
    #pragma unroll
    for (int i = 0; i < 4; ++i)
        #pragma unroll
        for (int j = 0; j < 4; ++j)
            acc[i][j] = (f32x4){0.f, 0.f, 0.f, 0.f};

    // eo staging map: lin = it*256+tid -> row = lin>>3 (coalesced: 8 lanes/row)
    const int erow0 = tid >> 3;         // it=0 row; it=1 row = erow0+32
    const int ekq   = tid & 7;          // float4 quad within the 32-k chunk
    const int ekg   = ekq >> 1, ehalf = ekq & 1;
    float nacc[2] = {0.f, 0.f};

    for (int kc = 0, c = 0; kc < E_; kc += 32, ++c) {
        __syncthreads();
        // ---- stage eo chunk: coalesced float4 loads, split, ds_write_b64
        #pragma unroll
        for (int it = 0; it < 2; ++it) {
            const int row = it * 32 + erow0;
            float4 v = *(const float4*)(eo + (size_t)(s0 + row) * (B_ * E_)
                                           + b * E_ + kc + ekq * 4);
            nacc[it] += v.x*v.x + v.y*v.y + v.z*v.z + v.w*v.w;
            unsigned short h0 = f2bf(v.x), h1 = f2bf(v.y);
            unsigned short h2 = f2bf(v.z), h3 = f2bf(v.w);
            unsigned int hp0 = (unsigned int)h0 | ((unsigned int)h1 << 16);
            unsigned int hp1 = (unsigned int)h2 | ((unsigned int)h3 << 16);
            unsigned int lp0 = (unsigned int)f2bf(v.x - bf2f(h0))
                             | ((unsigned int)f2bf(v.y - bf2f(h1)) << 16);
            unsigned int lp1 = (unsigned int)f2bf(v.z - bf2f(h2))
                             | ((unsigned int)f2bf(v.w - bf2f(h3)) << 16);
            const int u = ekg * 64 + row;
            *(uint2*)&eo_hl[(size_t)u * 8 + ehalf * 4]         = make_uint2(hp0, hp1);
            *(uint2*)&eo_hl[(size_t)(256 + u) * 8 + ehalf * 4] = make_uint2(lp0, lp1);
        }
        // ---- stage We chunk: fully coalesced async global->LDS (pre-packed)
        const unsigned short* gsrc = wepk + (size_t)c * 2048 * 8;
        #pragma unroll
        for (int it = 0; it < 8; ++it) {
            const int u = it * 256 + tid;
            __builtin_amdgcn_global_load_lds(
                (const __attribute__((address_space(1))) void*)(gsrc + (size_t)u * 8),
                (__attribute__((address_space(3))) void*)&we_hl[(size_t)u * 8],
                16, 0, 0);
        }
        __syncthreads();
        // ---- compute: B-frags once, then A-frags per m-tile
        short8 bh[4], bl[4];
        #pragma unroll
        for (int nt = 0; nt < 4; ++nt) {
            int bunit = lq * 256 + w * 64 + nt * 16 + lr;
            bh[nt] = *(const short8*)&we_hl[(size_t)bunit * 8];
            bl[nt] = *(const short8*)&we_hl[(size_t)(1024 + bunit) * 8];
        }
        #pragma unroll
        for (int mt = 0; mt < 4; ++mt) {
            int aunit = lq * 64 + mt * 16 + lr;
            short8 ah = *(const short8*)&eo_hl[(size_t)aunit * 8];
            short8 al = *(const short8*)&eo_hl[(size_t)(256 + aunit) * 8];
            #pragma unroll
            for (int nt = 0; nt < 4; ++nt) {
                acc[mt][nt] = __builtin_amdgcn_mfma_f32_16x16x32_bf16(ah, bh[nt], acc[mt][nt], 0, 0, 0);
                acc[mt][nt] = __builtin_amdgcn_mfma_f32_16x16x32_bf16(ah, bl[nt], acc[mt][nt], 0, 0, 0);
                acc[mt][nt] = __builtin_amdgcn_mfma_f32_16x16x32_bf16(al, bh[nt], acc[mt][nt], 0, 0, 0);
            }
        }
    }
    __syncthreads();   // all fragment reads done before LDS reuse

    // ---- epilogue: tanh + reduce over a
    float* red4 = (float*)we_hl;        // [64 cols][65] floats (16.6 KB < 32 KB)
    float pr[4];
    #pragma unroll
    for (int nt = 0; nt < 4; ++nt) pr[nt] = proj_lds[w * 64 + nt * 16 + lr];
    #pragma unroll
    for (int mt = 0; mt < 4; ++mt) {
        #pragma unroll
        for (int r = 0; r < 4; ++r) {
            float s = 0.f;
            #pragma unroll
            for (int nt = 0; nt < 4; ++nt)
                s += tanh_fast(pr[nt] + acc[mt][nt][r]);
            // C/D layout: col = lr (a-dim), row = mt*16 + lq*4 + r (s-dim)
            red4[(w * 16 + lr) * 65 + (mt * 16 + lq * 4 + r)] = s;
        }
    }
    npart[tid]       = nacc[0];   // partial of row tid>>3
    npart[256 + tid] = nacc[1];   // partial of row 32 + (tid>>3)
    __syncthreads();
    if (tid < 64) {
        float s = 0.f;
        #pragma unroll 8
        for (int c2 = 0; c2 < 64; ++c2) s += red4[c2 * 65 + tid];
        scores[b * S_ + s0 + tid] = s;
        const int base = (tid >> 5) * 256 + (tid & 31) * 8;
        float nq = 0.f;
        #pragma unroll
        for (int q = 0; q < 8; ++q) nq += npart[base + q];
        nsq[b * S_ + s0 + tid] = nq;
    }
}

// ---- Kernel C: softmax over S per b; writes p (into nsq_p, aliased) and
// attn_map = p * sqrt(nsq) in place of scores; zeroes attended region.
__global__ __launch_bounds__(256) void softmax_kernel(
    float* __restrict__ nsq_p, float* __restrict__ out)
{
    __shared__ float red[256];
    const int b = blockIdx.x;
    const int tid = threadIdx.x;
    float* scores = out + B_ * E_;

    float v[16];
    float m = -1e30f;
    #pragma unroll
    for (int i = 0; i < 16; ++i) {
        v[i] = scores[b * S_ + i * 256 + tid];
        m = fmaxf(m, v[i]);
    }
    red[tid] = m;
    __syncthreads();
    for (int off = 128; off > 0; off >>= 1) {
        if (tid < off) red[tid] = fmaxf(red[tid], red[tid + off]);
        __syncthreads();
    }
    m = red[0];
    __syncthreads();
    float sum = 0.f;
    #pragma unroll
    for (int i = 0; i < 16; ++i) { v[i] = expf(v[i] - m); sum += v[i]; }
    red[tid] = sum;
    __syncthreads();
    for (int off = 128; off > 0; off >>= 1) {
        if (tid < off) red[tid] += red[tid + off];
        __syncthreads();
    }
    const float inv = 1.f / red[0];
    #pragma unroll
    for (int i = 0; i < 16; ++i) {
        int s = i * 256 + tid;
        float pp = v[i] * inv;
        float nq = nsq_p[b * S_ + s];
        nsq_p[b * S_ + s] = pp;                    // p overwrites nsq in place
        scores[b * S_ + s] = pp * sqrtf(nq);       // attn_map in place
    }
    out[b * E_ + tid] = 0.f;  // zero attended region for kernel D's atomics
}

// ---- Kernel D: attended[b][e] += sum_{s} p[b][s] * eo[s][b][e]
// float4 per lane: wave reads a full 1 KB eo row per iteration (coalesced);
// p load is wave-uniform (tid>>6 constant within a wave).
__global__ __launch_bounds__(256) void attend_kernel(
    const float* __restrict__ eo, const float* __restrict__ p,
    float* __restrict__ out)
{
    __shared__ float4 red[4][64];
    const int tid = threadIdx.x;
    const int b   = blockIdx.x & (B_ - 1);
    const int ch  = blockIdx.x / B_;
    const int le  = tid & 63;
    const int sg  = tid >> 6;
    const int s0  = ch * SCH + sg * (SCH / 4);
    float4 acc = make_float4(0.f, 0.f, 0.f, 0.f);
    #pragma unroll 4
    for (int s = 0; s < SCH / 4; ++s) {
        float pv = p[b * S_ + s0 + s];
        float4 v = *(const float4*)(eo + (size_t)(s0 + s) * (B_ * E_)
                                       + b * E_ + le * 4);
        acc.x = fmaf(pv, v.x, acc.x);
        acc.y = fmaf(pv, v.y, acc.y);
        acc.z = fmaf(pv, v.z, acc.z);
        acc.w = fmaf(pv, v.w, acc.w);
    }
    red[sg][le] = acc;
    __syncthreads();
    if (tid < 64) {
        float4 a0 = red[0][tid], a1 = red[1][tid];
        float4 a2 = red[2][tid], a3 = red[3][tid];
        float* dst = out + b * E_ + tid * 4;
        atomicAdd(dst + 0, a0.x + a1.x + a2.x + a3.x);
        atomicAdd(dst + 1, a0.y + a1.y + a2.y + a3.y);
        atomicAdd(dst + 2, a0.z + a1.z + a2.z + a3.z);
        atomicAdd(dst + 3, a0.w + a1.w + a2.w + a3.w);
    }
}

extern "C" void kernel_launch(void* const* d_in, const int* in_sizes, int n_in,
                              void* d_out, int out_size, void* d_ws, size_t ws_size,
                              hipStream_t stream)
{
    const float* dh   = (const float*)d_in[0];  // (1,B,D)
    const float* eo   = (const float*)d_in[1];  // (S,B,E)
    const float* W    = (const float*)d_in[2];  // (A, D+E)
    const float* bias = (const float*)d_in[3];  // (A,)
    float* out = (float*)d_out;                 // [attended 8192 | attn_map 131072]
    float* ws  = (float*)d_ws;

    float* projb = ws;                            // 8192 floats
    float* nsqp  = ws + 8192;                     // 131072 floats (nsq, then p)
    unsigned short* wepk = (unsigned short*)(ws + 8192 + S_ * B_);  // 256 KB packed We
    float* scores = out + B_ * E_;  // staged in attn_map slot, overwritten by softmax

    wprep_kernel  <<<16384 / 256,     256, 0, stream>>>(W, wepk);
    proj_kernel   <<<B_,              256, 0, stream>>>(dh, W, bias, projb);
    scores_kernel <<<B_ * (S_ / 64),  256, 0, stream>>>(eo, wepk, projb, scores, nsqp);
    softmax_kernel<<<B_,              256, 0, stream>>>(nsqp, out);
    attend_kernel <<<B_ * (S_ / SCH), 256, 0, stream>>>(eo, nsqp, out);
}

// Round 4
// 268.521 us; speedup vs baseline: 4.4637x; 1.0128x over previous
//
#include <hip/hip_runtime.h>
#include <math.h>

#define B_  32
#define S_  4096
#define E_  256
#define A_  256
#define DE_ 512
#define SCH 128   // s-rows per block in attend kernel

typedef __attribute__((ext_vector_type(8))) short short8;
typedef __attribute__((ext_vector_type(4))) float f32x4;

__device__ inline unsigned short f2bf(float x) {
    unsigned int u = __float_as_uint(x);
    u += 0x7FFFu + ((u >> 16) & 1u);      // round-to-nearest-even
    return (unsigned short)(u >> 16);
}
__device__ inline float bf2f(unsigned short h) {
    return __uint_as_float(((unsigned int)h) << 16);
}
__device__ inline float tanh_fast(float x) {
    x = fminf(fmaxf(x, -15.f), 15.f);
    float t = __expf(2.f * x);
    return (t - 1.f) * __builtin_amdgcn_rcpf(t + 1.f);   // 1-instr rcp, ~1 ulp
}

// ---- Kernel W-prep: pack We = W[:,256:] split to bf16 hi/lo in the scores
// kernel's LDS fragment-linear layout: unit = c*2048 + plane*1024 + kg*256 + a,
// each unit = 8 bf16 (16 B) = We[a][c*32 + kg*8 .. +8].
// hi = truncated fp32 (mantissa AND), lo = RNE(x - hi): same 2^-17 accuracy,
// must match the eo split in scores_kernel.
__global__ __launch_bounds__(256) void wprep_kernel(
    const float* __restrict__ W, unsigned short* __restrict__ wepk)
{
    const int idx = blockIdx.x * 256 + threadIdx.x;   // unit 0..16383
    const int c     = idx >> 11;
    const int r     = idx & 2047;
    const int plane = r >> 10;        // 0 = hi, 1 = lo
    const int kg    = (r >> 8) & 3;
    const int a     = r & 255;
    const float* src = W + (size_t)a * DE_ + E_ + c * 32 + kg * 8;
    unsigned int pk[4];
    #pragma unroll
    for (int j = 0; j < 4; ++j) {
        float x0 = src[2 * j], x1 = src[2 * j + 1];
        unsigned int u0 = __float_as_uint(x0) & 0xFFFF0000u;
        unsigned int u1 = __float_as_uint(x1) & 0xFFFF0000u;
        if (plane) {
            unsigned short l0 = f2bf(x0 - __uint_as_float(u0));
            unsigned short l1 = f2bf(x1 - __uint_as_float(u1));
            pk[j] = (unsigned int)l0 | ((unsigned int)l1 << 16);
        } else {
            pk[j] = (u0 >> 16) | u1;
        }
    }
    *(uint4*)&wepk[(size_t)idx * 8] = make_uint4(pk[0], pk[1], pk[2], pk[3]);
}

// ---- Kernel A: proj[b][a] = bias[a] + sum_d dh[b][d] * W[a][d]
__global__ __launch_bounds__(256) void proj_kernel(
    const float* __restrict__ dh, const float* __restrict__ W,
    const float* __restrict__ bias, float* __restrict__ proj)
{
    __shared__ float dh_lds[E_];
    const int b = blockIdx.x;
    const int a = threadIdx.x;
    dh_lds[a] = dh[b * E_ + a];
    __syncthreads();
    float acc = bias[a];
    const float* wrow = W + (size_t)a * DE_;
    #pragma unroll
    for (int d = 0; d < E_; d += 4) {
        float4 w = *(const float4*)(wrow + d);
        acc += dh_lds[d] * w.x + dh_lds[d+1] * w.y
             + dh_lds[d+2] * w.z + dh_lds[d+3] * w.w;
    }
    proj[b * A_ + a] = acc;
}

// ---- Kernel B: scores[b][s] = sum_a tanh(proj[b][a] + eo[b,s,:].We[a,:])
//                nsq[b][s]    = ||eo[b,s,:]||^2
// Split-bf16 MFMA (3 products): block = 64 s x 256 a, wave = 64 s x 64 a.
// LDS = 40960 B exactly -> 4 blocks/CU with __launch_bounds__(256,4).
__global__ __launch_bounds__(256, 4) void scores_kernel(
    const float* __restrict__ eo,
    const unsigned short* __restrict__ wepk,
    const float* __restrict__ proj,
    float* __restrict__ scores, float* __restrict__ nsq)
{
    __shared__ __align__(16) unsigned short we_hl[2 * 4 * 256 * 8]; // 32768 B
    __shared__ __align__(16) unsigned short eo_hl[2 * 4 * 64 * 8];  // 8192 B

    const int tid = threadIdx.x;
    const int b   = blockIdx.x & (B_ - 1);
    const int s0  = (blockIdx.x / B_) * 64;
    const int w   = tid >> 6;     // wave id 0..3 -> a-range w*64
    const int l   = tid & 63;
    const int lq  = l >> 4;       // quad 0..3 -> k-group
    const int lr  = l & 15;       // row/col within tile
    const int lqx = (lq & 1) << 2;  // A-frag read swizzle (matches write)

    // proj values this lane needs in the epilogue: 4 registers, no LDS
    float pr[4];
    #pragma unroll
    for (int nt = 0; nt < 4; ++nt) pr[nt] = proj[b * A_ + w * 64 + nt * 16 + lr];

    f32x4 acc[4][4];
    #pragma unroll
    for (int i = 0; i < 4; ++i)
        #pragma unroll
        for (int j = 0; j < 4; ++j)
            acc[i][j] = (f32x4){0.f, 0.f, 0.f, 0.f};

    // eo staging map: 8 lanes per row (coalesced float4 reads)
    const int erow0 = tid >> 3;         // it=0 row; it=1 row = erow0+32
    const int ekq   = tid & 7;
    const int ekg   = ekq >> 1, ehalf = ekq & 1;
    const int esw   = (ekg & 1) << 2;   // XOR swizzle: 4-way bank conflict -> 2-way
    float nacc[2] = {0.f, 0.f};

    for (int kc = 0, c = 0; kc < E_; kc += 32, ++c) {
        __syncthreads();
        // ---- stage eo chunk: coalesced float4 loads, trunc hi / RNE lo split
        #pragma unroll
        for (int it = 0; it < 2; ++it) {
            const int row = it * 32 + erow0;
            float4 v = *(const float4*)(eo + (size_t)(s0 + row) * (B_ * E_)
                                           + b * E_ + kc + ekq * 4);
            nacc[it] += v.x*v.x + v.y*v.y + v.z*v.z + v.w*v.w;
            unsigned int ux = __float_as_uint(v.x) & 0xFFFF0000u;
            unsigned int uy = __float_as_uint(v.y) & 0xFFFF0000u;
            unsigned int uz = __float_as_uint(v.z) & 0xFFFF0000u;
            unsigned int uw = __float_as_uint(v.w) & 0xFFFF0000u;
            unsigned int hp0 = (ux >> 16) | uy;
            unsigned int hp1 = (uz >> 16) | uw;
            unsigned int lp0 = (unsigned int)f2bf(v.x - __uint_as_float(ux))
                             | ((unsigned int)f2bf(v.y - __uint_as_float(uy)) << 16);
            unsigned int lp1 = (unsigned int)f2bf(v.z - __uint_as_float(uz))
                             | ((unsigned int)f2bf(v.w - __uint_as_float(uw)) << 16);
            const int u = ekg * 64 + (row ^ esw);
            *(uint2*)&eo_hl[(size_t)u * 8 + ehalf * 4]         = make_uint2(hp0, hp1);
            *(uint2*)&eo_hl[(size_t)(256 + u) * 8 + ehalf * 4] = make_uint2(lp0, lp1);
        }
        // ---- stage We chunk: fully coalesced async global->LDS (pre-packed)
        const unsigned short* gsrc = wepk + (size_t)c * 2048 * 8;
        #pragma unroll
        for (int it = 0; it < 8; ++it) {
            const int u = it * 256 + tid;
            __builtin_amdgcn_global_load_lds(
                (const __attribute__((address_space(1))) void*)(gsrc + (size_t)u * 8),
                (__attribute__((address_space(3))) void*)&we_hl[(size_t)u * 8],
                16, 0, 0);
        }
        __syncthreads();
        // ---- compute: B-frags once, then A-frags per m-tile
        short8 bh[4], bl[4];
        #pragma unroll
        for (int nt = 0; nt < 4; ++nt) {
            int bunit = lq * 256 + w * 64 + nt * 16 + lr;
            bh[nt] = *(const short8*)&we_hl[(size_t)bunit * 8];
            bl[nt] = *(const short8*)&we_hl[(size_t)(1024 + bunit) * 8];
        }
        #pragma unroll
        for (int mt = 0; mt < 4; ++mt) {
            int aunit = lq * 64 + ((mt * 16 + lr) ^ lqx);
            short8 ah = *(const short8*)&eo_hl[(size_t)aunit * 8];
            short8 al = *(const short8*)&eo_hl[(size_t)(256 + aunit) * 8];
            #pragma unroll
            for (int nt = 0; nt < 4; ++nt) {
                acc[mt][nt] = __builtin_amdgcn_mfma_f32_16x16x32_bf16(ah, bh[nt], acc[mt][nt], 0, 0, 0);
                acc[mt][nt] = __builtin_amdgcn_mfma_f32_16x16x32_bf16(ah, bl[nt], acc[mt][nt], 0, 0, 0);
                acc[mt][nt] = __builtin_amdgcn_mfma_f32_16x16x32_bf16(al, bh[nt], acc[mt][nt], 0, 0, 0);
            }
        }
    }
    __syncthreads();   // all fragment reads done before LDS reuse

    // ---- epilogue: tanh + reduce over a (overlays inside we_hl, all past barrier)
    float* red4  = (float*)we_hl;            // [64 cols][65] floats = 16640 B
    float* npart = red4 + 64 * 65;           // 512 floats
    float* qpart = npart + 512;              // 256 floats (total 19712 < 32768)
    #pragma unroll
    for (int mt = 0; mt < 4; ++mt) {
        #pragma unroll
        for (int r = 0; r < 4; ++r) {
            float s = 0.f;
            #pragma unroll
            for (int nt = 0; nt < 4; ++nt)
                s += tanh_fast(pr[nt] + acc[mt][nt][r]);
            // C/D layout: col = lr (a-dim), row = mt*16 + lq*4 + r (s-dim)
            red4[(w * 16 + lr) * 65 + (mt * 16 + lq * 4 + r)] = s;
        }
    }
    npart[tid]       = nacc[0];   // partial of row tid>>3
    npart[256 + tid] = nacc[1];   // partial of row 32 + (tid>>3)
    __syncthreads();
    {   // 256-thread reduction: thread (q, r) sums 16 of 64 columns of row r
        const int r = tid & 63, q = tid >> 6;
        float s = 0.f;
        #pragma unroll
        for (int c2 = q * 16; c2 < q * 16 + 16; ++c2) s += red4[c2 * 65 + r];
        qpart[q * 64 + r] = s;
    }
    __syncthreads();
    if (tid < 64) {
        scores[b * S_ + s0 + tid] = qpart[tid] + qpart[64 + tid]
                                  + qpart[128 + tid] + qpart[192 + tid];
        const int base = (tid >> 5) * 256 + (tid & 31) * 8;
        float nq = 0.f;
        #pragma unroll
        for (int q2 = 0; q2 < 8; ++q2) nq += npart[base + q2];
        nsq[b * S_ + s0 + tid] = nq;
    }
}

// ---- Kernel C: softmax over S per b; writes p (into nsq_p, aliased) and
// attn_map = p * sqrt(nsq) in place of scores; zeroes attended region.
__global__ __launch_bounds__(256) void softmax_kernel(
    float* __restrict__ nsq_p, float* __restrict__ out)
{
    __shared__ float red[256];
    const int b = blockIdx.x;
    const int tid = threadIdx.x;
    float* scores = out + B_ * E_;

    float v[16];
    float m = -1e30f;
    #pragma unroll
    for (int i = 0; i < 16; ++i) {
        v[i] = scores[b * S_ + i * 256 + tid];
        m = fmaxf(m, v[i]);
    }
    red[tid] = m;
    __syncthreads();
    for (int off = 128; off > 0; off >>= 1) {
        if (tid < off) red[tid] = fmaxf(red[tid], red[tid + off]);
        __syncthreads();
    }
    m = red[0];
    __syncthreads();
    float sum = 0.f;
    #pragma unroll
    for (int i = 0; i < 16; ++i) { v[i] = expf(v[i] - m); sum += v[i]; }
    red[tid] = sum;
    __syncthreads();
    for (int off = 128; off > 0; off >>= 1) {
        if (tid < off) red[tid] += red[tid + off];
        __syncthreads();
    }
    const float inv = 1.f / red[0];
    #pragma unroll
    for (int i = 0; i < 16; ++i) {
        int s = i * 256 + tid;
        float pp = v[i] * inv;
        float nq = nsq_p[b * S_ + s];
        nsq_p[b * S_ + s] = pp;                    // p overwrites nsq in place
        scores[b * S_ + s] = pp * sqrtf(nq);       // attn_map in place
    }
    out[b * E_ + tid] = 0.f;  // zero attended region for kernel D's atomics
}

// ---- Kernel D: attended[b][e] += sum_{s} p[b][s] * eo[s][b][e]
__global__ __launch_bounds__(256) void attend_kernel(
    const float* __restrict__ eo, const float* __restrict__ p,
    float* __restrict__ out)
{
    __shared__ float4 red[4][64];
    const int tid = threadIdx.x;
    const int b   = blockIdx.x & (B_ - 1);
    const int ch  = blockIdx.x / B_;
    const int le  = tid & 63;
    const int sg  = tid >> 6;
    const int s0  = ch * SCH + sg * (SCH / 4);
    float4 acc = make_float4(0.f, 0.f, 0.f, 0.f);
    #pragma unroll 4
    for (int s = 0; s < SCH / 4; ++s) {
        float pv = p[b * S_ + s0 + s];
        float4 v = *(const float4*)(eo + (size_t)(s0 + s) * (B_ * E_)
                                       + b * E_ + le * 4);
        acc.x = fmaf(pv, v.x, acc.x);
        acc.y = fmaf(pv, v.y, acc.y);
        acc.z = fmaf(pv, v.z, acc.z);
        acc.w = fmaf(pv, v.w, acc.w);
    }
    red[sg][le] = acc;
    __syncthreads();
    if (tid < 64) {
        float4 a0 = red[0][tid], a1 = red[1][tid];
        float4 a2 = red[2][tid], a3 = red[3][tid];
        float* dst = out + b * E_ + tid * 4;
        atomicAdd(dst + 0, a0.x + a1.x + a2.x + a3.x);
        atomicAdd(dst + 1, a0.y + a1.y + a2.y + a3.y);
        atomicAdd(dst + 2, a0.z + a1.z + a2.z + a3.z);
        atomicAdd(dst + 3, a0.w + a1.w + a2.w + a3.w);
    }
}

extern "C" void kernel_launch(void* const* d_in, const int* in_sizes, int n_in,
                              void* d_out, int out_size, void* d_ws, size_t ws_size,
                              hipStream_t stream)
{
    const float* dh   = (const float*)d_in[0];  // (1,B,D)
    const float* eo   = (const float*)d_in[1];  // (S,B,E)
    const float* W    = (const float*)d_in[2];  // (A, D+E)
    const float* bias = (const float*)d_in[3];  // (A,)
    float* out = (float*)d_out;                 // [attended 8192 | attn_map 131072]
    float* ws  = (float*)d_ws;

    float* projb = ws;                            // 8192 floats
    float* nsqp  = ws + 8192;                     // 131072 floats (nsq, then p)
    unsigned short* wepk = (unsigned short*)(ws + 8192 + S_ * B_);  // 256 KB packed We
    float* scores = out + B_ * E_;  // staged in attn_map slot, overwritten by softmax

    wprep_kernel  <<<16384 / 256,     256, 0, stream>>>(W, wepk);
    proj_kernel   <<<B_,              256, 0, stream>>>(dh, W, bias, projb);
    scores_kernel <<<B_ * (S_ / 64),  256, 0, stream>>>(eo, wepk, projb, scores, nsqp);
    softmax_kernel<<<B_,              256, 0, stream>>>(nsqp, out);
    attend_kernel <<<B_ * (S_ / SCH), 256, 0, stream>>>(eo, nsqp, out);
}